// Round 5
// baseline (1409.260 us; speedup 1.0000x reference)
//
#include <hip/hip_runtime.h>
#include <hip/hip_bf16.h>
#include <math.h>

// Problem constants
#define Bq 4
#define Sq 1024
#define Eq 1024
#define Hq 16
#define Dq 64

// ---------------------------------------------------------------------------
// GEMM: C[M,N] = (A[M,K] @ Bw[N,K]^T + bias[N]) * scale   (torch Linear style)
// 128x128 tile, BK=16, 256 threads, 8x8 register micro-tile. fp32.
// Per kk: 64 FMA (128 wave-cyc) vs 4 ds_read_b128 (~48 cyc) -> FMA-dominant
// (r4's 64x64/4x4 was 16 FMA vs 2 b128 + staging -> ~30% of fp32 peak).
// ---------------------------------------------------------------------------
#define GBK 16
#define GPAD 132  // 128 + 4: row stride 528B (16B-aligned); write bank stride 4 -> 2-way (free)

__global__ __launch_bounds__(256, 2) void gemm128(
    const float* __restrict__ A,    // [M,K]
    const float* __restrict__ Bw,   // [N,K]
    const float* __restrict__ bias, // [N]
    float* __restrict__ C,          // [M,N]
    int M, int N, int K, float scale)
{
    __shared__ float As[GBK][GPAD];
    __shared__ float Bs[GBK][GPAD];

    const int bm = blockIdx.y * 128;
    const int bn = blockIdx.x * 128;
    const int t  = threadIdx.x;
    const int tn = t & 15;   // 0..15 -> 8-col group
    const int tm = t >> 4;   // 0..15 -> 8-row group
    const int lk = t & 15;
    const int lm = t >> 4;

    float acc[8][8] = {};

    for (int k0 = 0; k0 < K; k0 += GBK) {
#pragma unroll
        for (int r = 0; r < 8; r++) {
            As[lk][lm + 16 * r] = A[(size_t)(bm + lm + 16 * r) * K + k0 + lk];
            Bs[lk][lm + 16 * r] = Bw[(size_t)(bn + lm + 16 * r) * K + k0 + lk];
        }
        __syncthreads();
#pragma unroll
        for (int kk = 0; kk < GBK; kk++) {
            float a[8], b[8];
#pragma unroll
            for (int i = 0; i < 8; i++) a[i] = As[kk][tm * 8 + i];
#pragma unroll
            for (int j = 0; j < 8; j++) b[j] = Bs[kk][tn * 8 + j];
#pragma unroll
            for (int i = 0; i < 8; i++)
#pragma unroll
                for (int j = 0; j < 8; j++)
                    acc[i][j] += a[i] * b[j];
        }
        __syncthreads();
    }

    const float4 bb0 = *(const float4*)(bias + bn + tn * 8);
    const float4 bb1 = *(const float4*)(bias + bn + tn * 8 + 4);
#pragma unroll
    for (int i = 0; i < 8; i++) {
        const int row = bm + tm * 8 + i;
        float4 o0, o1;
        o0.x = (acc[i][0] + bb0.x) * scale;
        o0.y = (acc[i][1] + bb0.y) * scale;
        o0.z = (acc[i][2] + bb0.z) * scale;
        o0.w = (acc[i][3] + bb0.w) * scale;
        o1.x = (acc[i][4] + bb1.x) * scale;
        o1.y = (acc[i][5] + bb1.y) * scale;
        o1.z = (acc[i][6] + bb1.z) * scale;
        o1.w = (acc[i][7] + bb1.w) * scale;
        *(float4*)(C + (size_t)row * N + bn + tn * 8)     = o0;
        *(float4*)(C + (size_t)row * N + bn + tn * 8 + 4) = o1;
    }
}

// ---------------------------------------------------------------------------
// Same GEMM, epilogue writes the K projection transposed per head:
// Kt[((b*H + h)*D + d) * S + s] so attn_scores reads K coalesced along s.
// ---------------------------------------------------------------------------
__global__ __launch_bounds__(256, 2) void gemm128_kt(
    const float* __restrict__ A,    // [M,K]  (x)
    const float* __restrict__ Bw,   // [N,K]  (Wk)
    const float* __restrict__ bias, // [N]
    float* __restrict__ Kt,         // [B*H*D, S]
    int M, int N, int K, float scale)
{
    __shared__ float As[GBK][GPAD];
    __shared__ float Bs[GBK][GPAD];

    const int bm = blockIdx.y * 128;
    const int bn = blockIdx.x * 128;
    const int t  = threadIdx.x;
    const int tn = t & 15;
    const int tm = t >> 4;
    const int lk = t & 15;
    const int lm = t >> 4;

    float acc[8][8] = {};

    for (int k0 = 0; k0 < K; k0 += GBK) {
#pragma unroll
        for (int r = 0; r < 8; r++) {
            As[lk][lm + 16 * r] = A[(size_t)(bm + lm + 16 * r) * K + k0 + lk];
            Bs[lk][lm + 16 * r] = Bw[(size_t)(bn + lm + 16 * r) * K + k0 + lk];
        }
        __syncthreads();
#pragma unroll
        for (int kk = 0; kk < GBK; kk++) {
            float a[8], b[8];
#pragma unroll
            for (int i = 0; i < 8; i++) a[i] = As[kk][tm * 8 + i];
#pragma unroll
            for (int j = 0; j < 8; j++) b[j] = Bs[kk][tn * 8 + j];
#pragma unroll
            for (int i = 0; i < 8; i++)
#pragma unroll
                for (int j = 0; j < 8; j++)
                    acc[i][j] += a[i] * b[j];
        }
        __syncthreads();
    }

    // Transposed epilogue: 128-row tile lies within one batch (1024 % 128 == 0).
    const int row0 = bm + tm * 8;        // b*Sq + s
    const int b    = row0 >> 10;
    const int s    = row0 & (Sq - 1);
#pragma unroll
    for (int j = 0; j < 8; j++) {
        const int col = bn + tn * 8 + j; // h*Dq + d
        const int h = col >> 6;
        const int d = col & (Dq - 1);
        const float bb = bias[col];
        float4 o0, o1;
        o0.x = (acc[0][j] + bb) * scale;
        o0.y = (acc[1][j] + bb) * scale;
        o0.z = (acc[2][j] + bb) * scale;
        o0.w = (acc[3][j] + bb) * scale;
        o1.x = (acc[4][j] + bb) * scale;
        o1.y = (acc[5][j] + bb) * scale;
        o1.z = (acc[6][j] + bb) * scale;
        o1.w = (acc[7][j] + bb) * scale;
        float* p = Kt + (size_t)((b * Hq + h) * Dq + d) * Sq + s;
        *(float4*)p       = o0;
        *(float4*)(p + 4) = o1;
    }
}

// ---------------------------------------------------------------------------
// Scores + softmax: one block per (b,h, 8-q group). 256 threads.
// Thread t owns k-columns {4t..4t+3}: all global accesses coalesced float4.
// (r4 measured: 285 us, VALUBusy 48%, VGPR 36, no spill. Unchanged.)
// ---------------------------------------------------------------------------
#define QB 8

__global__ __launch_bounds__(256, 2) void attn_scores(
    const float* __restrict__ Q,     // [B*S, E] (pre-scaled)
    const float* __restrict__ Kt,    // [B*H*D, S] head-transposed K
    const float* __restrict__ bias,  // [B,H,S,S]
    const int*   __restrict__ mask,  // [B,S]
    float* __restrict__ W)           // [B,H,S,S]
{
    const int bid = blockIdx.x;
    const int qc = bid & (Sq / QB - 1);       // 0..127
    const int h  = (bid >> 7) & (Hq - 1);
    const int b  = bid >> 11;
    const int q0 = qc * QB;

    __shared__ __align__(16) float qs[QB][Dq];
    __shared__ float redm[QB][4];
    __shared__ float reds[QB][4];

    const int t = threadIdx.x;

    // load 8 q rows (8*64 floats = 128 float4s)
    if (t < 128) {
        const int qq = t >> 4;   // 16 float4 per row
        const int c4 = t & 15;
        ((float4*)qs[qq])[c4] =
            *(const float4*)(Q + ((size_t)(b * Sq + q0 + qq)) * Eq + h * Dq + c4 * 4);
    }
    __syncthreads();

    const float* Ktp = Kt + (size_t)(b * Hq + h) * Dq * Sq;

    float sc[4][QB];
#pragma unroll
    for (int j = 0; j < 4; j++)
#pragma unroll
        for (int qq = 0; qq < QB; qq++) sc[j][qq] = 0.f;

#pragma unroll 1
    for (int d = 0; d < Dq; d++) {
        const float4 kt = *(const float4*)(Ktp + (size_t)d * Sq + 4 * t);
#pragma unroll
        for (int qq = 0; qq < QB; qq++) {
            const float qv = qs[qq][d];
            sc[0][qq] += kt.x * qv;
            sc[1][qq] += kt.y * qv;
            sc[2][qq] += kt.z * qv;
            sc[3][qq] += kt.w * qv;
        }
    }

    // bias + mask + per-thread max
    const int*  mrow = mask + b * Sq;
    const int4  mv   = *(const int4*)(mrow + 4 * t);
    const float* biasBase = bias + ((size_t)(b * Hq + h) * Sq + q0) * Sq;

    float mx[QB];
#pragma unroll
    for (int qq = 0; qq < QB; qq++) {
        const float4 bv = *(const float4*)(biasBase + (size_t)qq * Sq + 4 * t);
        float d0 = (mv.x != 0) ? -INFINITY : (sc[0][qq] + bv.x);
        float d1 = (mv.y != 0) ? -INFINITY : (sc[1][qq] + bv.y);
        float d2 = (mv.z != 0) ? -INFINITY : (sc[2][qq] + bv.z);
        float d3 = (mv.w != 0) ? -INFINITY : (sc[3][qq] + bv.w);
        sc[0][qq] = d0; sc[1][qq] = d1; sc[2][qq] = d2; sc[3][qq] = d3;
        mx[qq] = fmaxf(fmaxf(d0, d1), fmaxf(d2, d3));
    }

    const int lane = t & 63;
    const int wid  = t >> 6;

    // wave-level max reduce, then cross-wave (4 waves)
#pragma unroll
    for (int off = 32; off > 0; off >>= 1)
#pragma unroll
        for (int qq = 0; qq < QB; qq++)
            mx[qq] = fmaxf(mx[qq], __shfl_xor(mx[qq], off));
    if (lane == 0) {
#pragma unroll
        for (int qq = 0; qq < QB; qq++) redm[qq][wid] = mx[qq];
    }
    __syncthreads();
#pragma unroll
    for (int qq = 0; qq < QB; qq++)
        mx[qq] = fmaxf(fmaxf(redm[qq][0], redm[qq][1]),
                       fmaxf(redm[qq][2], redm[qq][3]));

    // exp + per-thread sum
    float ls[QB];
#pragma unroll
    for (int qq = 0; qq < QB; qq++) ls[qq] = 0.f;
#pragma unroll
    for (int j = 0; j < 4; j++)
#pragma unroll
        for (int qq = 0; qq < QB; qq++) {
            const float e = __expf(sc[j][qq] - mx[qq]);  // exp(-inf) = 0 for masked
            sc[j][qq] = e;
            ls[qq] += e;
        }

    // wave-level sum reduce, then cross-wave
#pragma unroll
    for (int off = 32; off > 0; off >>= 1)
#pragma unroll
        for (int qq = 0; qq < QB; qq++)
            ls[qq] += __shfl_xor(ls[qq], off);
    if (lane == 0) {
#pragma unroll
        for (int qq = 0; qq < QB; qq++) reds[qq][wid] = ls[qq];
    }
    __syncthreads();

    float inv[QB];
#pragma unroll
    for (int qq = 0; qq < QB; qq++)
        inv[qq] = 1.0f / (reds[qq][0] + reds[qq][1] + reds[qq][2] + reds[qq][3]);

    // write normalized weights (coalesced float4 along k)
    float* wBase = W + ((size_t)(b * Hq + h) * Sq + q0) * Sq;
#pragma unroll
    for (int qq = 0; qq < QB; qq++) {
        float4 o;
        o.x = sc[0][qq] * inv[qq];
        o.y = sc[1][qq] * inv[qq];
        o.z = sc[2][qq] * inv[qq];
        o.w = sc[3][qq] * inv[qq];
        *(float4*)(wBase + (size_t)qq * Sq + 4 * t) = o;
    }
}

// ---------------------------------------------------------------------------
// PV: AO[b,q,h*64+d] = sum_k W[b,h,q,k] * V[b,k,h*64+d]
// Batched GEMM per (b,h): C[1024 q][64 d] = W @ V.
// 128x64 tile, BK=16, 256 threads, 8x4 micro-tile (32 FMA vs 3 b128 per kk).
// ---------------------------------------------------------------------------
#define PVPAD 68

__global__ __launch_bounds__(256, 2) void attn_pv(
    const float* __restrict__ W,  // [B,H,S,S]
    const float* __restrict__ V,  // [B*S, E]
    float* __restrict__ AO)       // [B*S, E]
{
    const int bh = blockIdx.y;          // 0..63
    const int h  = bh & (Hq - 1);
    const int b  = bh >> 4;
    const int bm = blockIdx.x * 128;    // q tile base

    __shared__ float Ws[GBK][GPAD];     // [kk][q] 128 wide
    __shared__ float Vs[GBK][PVPAD];    // [kk][d] 64 wide

    const float* Wbase = W + (size_t)(b * Hq + h) * Sq * Sq;
    const float* Vbase = V + (size_t)b * Sq * Eq + h * Dq;

    const int t  = threadIdx.x;
    const int tn = t & 15;   // d-group: 16 x 4 = 64
    const int tm = t >> 4;   // q-group: 16 x 8 = 128
    const int lk = t & 15;
    const int lm = t >> 4;
    const int ld = t & 63;
    const int lr = t >> 6;   // 0..3

    float acc[8][4] = {};

    for (int k0 = 0; k0 < Sq; k0 += GBK) {
#pragma unroll
        for (int r = 0; r < 8; r++)
            Ws[lk][lm + 16 * r] = Wbase[(size_t)(bm + lm + 16 * r) * Sq + k0 + lk];
#pragma unroll
        for (int r = 0; r < 4; r++)
            Vs[lr + 4 * r][ld] = Vbase[(size_t)(k0 + lr + 4 * r) * Eq + ld];
        __syncthreads();
#pragma unroll
        for (int kk = 0; kk < GBK; kk++) {
            float a[8], bb[4];
#pragma unroll
            for (int i = 0; i < 8; i++) a[i] = Ws[kk][tm * 8 + i];
#pragma unroll
            for (int j = 0; j < 4; j++) bb[j] = Vs[kk][tn * 4 + j];
#pragma unroll
            for (int i = 0; i < 8; i++)
#pragma unroll
                for (int j = 0; j < 4; j++)
                    acc[i][j] += a[i] * bb[j];
        }
        __syncthreads();
    }

#pragma unroll
    for (int i = 0; i < 8; i++) {
        float4 o;
        o.x = acc[i][0]; o.y = acc[i][1]; o.z = acc[i][2]; o.w = acc[i][3];
        *(float4*)(AO + (size_t)(b * Sq + bm + tm * 8 + i) * Eq + h * Dq + tn * 4) = o;
    }
}

// ---------------------------------------------------------------------------
extern "C" void kernel_launch(void* const* d_in, const int* in_sizes, int n_in,
                              void* d_out, int out_size, void* d_ws, size_t ws_size,
                              hipStream_t stream) {
    const float* x         = (const float*)d_in[0];
    const float* attn_bias = (const float*)d_in[1];
    const int*   mask      = (const int*)d_in[2];
    const float* Wq = (const float*)d_in[3];
    const float* bq = (const float*)d_in[4];
    const float* Wk = (const float*)d_in[5];
    const float* bk = (const float*)d_in[6];
    const float* Wv = (const float*)d_in[7];
    const float* bv = (const float*)d_in[8];
    const float* Wo = (const float*)d_in[9];
    const float* bo = (const float*)d_in[10];

    float* out    = (float*)d_out;                       // [B,S,E]
    float* attn_w = out + (size_t)Bq * Sq * Eq;          // [B,H,S,S]

    const size_t rows = (size_t)Bq * Sq;                 // 4096
    float* Q  = (float*)d_ws;                            // [4096,1024]
    float* Kt = Q + rows * Eq;                           // [B*H*D, S] transposed K
    float* V  = Kt + rows * Eq;
    float* AO = Q;  // reuse Q's slot after scores are done

    const dim3 gemm_grid(Eq / 128, (int)(rows / 128));   // 8 x 32 = 256 blocks
    const float scaling = 0.125f;                        // D^-0.5

    gemm128<<<gemm_grid, 256, 0, stream>>>(x, Wq, bq, Q, (int)rows, Eq, Eq, scaling);
    gemm128_kt<<<gemm_grid, 256, 0, stream>>>(x, Wk, bk, Kt, (int)rows, Eq, Eq, 1.0f);
    gemm128<<<gemm_grid, 256, 0, stream>>>(x, Wv, bv, V, (int)rows, Eq, Eq, 1.0f);

    attn_scores<<<Bq * Hq * (Sq / QB), 256, 0, stream>>>(Q, Kt, attn_bias, mask, attn_w);

    const dim3 pv_grid(Sq / 128, Bq * Hq);               // 8 x 64
    attn_pv<<<pv_grid, 256, 0, stream>>>(attn_w, V, AO);

    gemm128<<<gemm_grid, 256, 0, stream>>>(AO, Wo, bo, out, (int)rows, Eq, Eq, 1.0f);
}

// Round 6
// 892.135 us; speedup vs baseline: 1.5796x; 1.5796x over previous
//
#include <hip/hip_runtime.h>
#include <hip/hip_bf16.h>
#include <math.h>

// Problem constants
#define Bq 4
#define Sq 1024
#define Eq 1024
#define Hq 16
#define Dq 64

// ---------------------------------------------------------------------------
// Split-bf16 MFMA GEMM skeleton:  C = A[M,K] @ Bw[N,K]^T  (+bias)*scale
// fp32 operands split as x ~ hi(bf16) + lo(bf16); product via 3 MFMAs
// (hi*hi + hi*lo + lo*hi), fp32 accumulate -> ~fp32 accuracy (~2^-18 rel).
// Tile: BM=128 x BN=64, BK=32, 256 threads (4 waves), wave = 32x64 = 8 MFMA
// tiles of 16x16x32. Grid 512 blocks = 2 blocks/CU (r5 lesson: 256 blocks =
// 1/CU = no TLP). Verified layouts: A/B frag row/col = l&15, k=(l>>4)*8+j;
// C/D col = l&15, row = (l>>4)*4 + r  [learn_hip m89].
// ---------------------------------------------------------------------------
#define BM 128
#define BN 64
#define BKK 32
#define LPAD 56  // bf16 row stride: 112B = multiple of 16B (aligned b128 frag
                 // reads), dword stride 28 -> 2-way bank aliasing (free)

typedef __attribute__((ext_vector_type(8))) short bf16x8;
typedef __attribute__((ext_vector_type(4))) float f32x4;

__device__ inline unsigned short bf16r(float x) {
    union { float f; unsigned u; } v; v.f = x;
    unsigned r = v.u + 0x7FFFu + ((v.u >> 16) & 1u);  // RNE
    return (unsigned short)(r >> 16);
}
__device__ inline float bf16f(unsigned short h) {
    union { unsigned u; float f; } v; v.u = ((unsigned)h) << 16; return v.f;
}
__device__ inline void cvt_hl(float4 v, uint2* hp, uint2* lp) {
    unsigned short h0 = bf16r(v.x), h1 = bf16r(v.y), h2 = bf16r(v.z), h3 = bf16r(v.w);
    unsigned short l0 = bf16r(v.x - bf16f(h0)), l1 = bf16r(v.y - bf16f(h1));
    unsigned short l2 = bf16r(v.z - bf16f(h2)), l3 = bf16r(v.w - bf16f(h3));
    hp->x = (unsigned)h0 | ((unsigned)h1 << 16);
    hp->y = (unsigned)h2 | ((unsigned)h3 << 16);
    lp->x = (unsigned)l0 | ((unsigned)l1 << 16);
    lp->y = (unsigned)l2 | ((unsigned)l3 << 16);
}

// EPI 0: C[row][col] = (acc + bias[col]) * scale           (normal layout)
// EPI 1: Ct[((b*H+h)*D+d)*S + s] = (acc + bias[col])*scale (head-transposed)
template <int EPI>
__global__ __launch_bounds__(256, 2) void gemm_mfma(
    const float* __restrict__ A,    // [M,K]
    const float* __restrict__ Bw,   // [N,K]
    const float* __restrict__ bias, // [N]
    float* __restrict__ C,
    int M, int N, int K, float scale)
{
    __shared__ unsigned short Ah[BM][LPAD];
    __shared__ unsigned short Al[BM][LPAD];
    __shared__ unsigned short Bh[BN][LPAD];
    __shared__ unsigned short Bl[BN][LPAD];

    const int bm = blockIdx.y * BM;
    const int bn = blockIdx.x * BN;
    const int t  = threadIdx.x;
    const int l  = t & 63;
    const int w  = t >> 6;         // wave 0..3 -> m-strip w*32
    const int ln = l & 15;
    const int ko = (l >> 4) * 8;   // k-offset of this lane's frag

    const int r0 = t >> 3;         // 0..31 staging row
    const int kc = (t & 7) * 4;    // staging k (float4)

    f32x4 acc[2][4] = {};

#pragma unroll 1
    for (int k0 = 0; k0 < K; k0 += BKK) {
        // stage A-tile 128x32 fp32 -> hi/lo bf16
#pragma unroll
        for (int rr = 0; rr < 4; rr++) {
            const int m = r0 + 32 * rr;
            float4 v = *(const float4*)(A + (size_t)(bm + m) * K + k0 + kc);
            uint2 hp, lp; cvt_hl(v, &hp, &lp);
            *(uint2*)&Ah[m][kc] = hp;
            *(uint2*)&Al[m][kc] = lp;
        }
        // stage B-tile 64x32
#pragma unroll
        for (int rr = 0; rr < 2; rr++) {
            const int n = r0 + 32 * rr;
            float4 v = *(const float4*)(Bw + (size_t)(bn + n) * K + k0 + kc);
            uint2 hp, lp; cvt_hl(v, &hp, &lp);
            *(uint2*)&Bh[n][kc] = hp;
            *(uint2*)&Bl[n][kc] = lp;
        }
        __syncthreads();

        bf16x8 ah[2], al[2];
#pragma unroll
        for (int i = 0; i < 2; i++) {
            const int m = w * 32 + i * 16 + ln;
            ah[i] = *(const bf16x8*)&Ah[m][ko];
            al[i] = *(const bf16x8*)&Al[m][ko];
        }
#pragma unroll
        for (int j = 0; j < 4; j++) {
            const int n = j * 16 + ln;
            const bf16x8 bh_ = *(const bf16x8*)&Bh[n][ko];
            const bf16x8 bl_ = *(const bf16x8*)&Bl[n][ko];
#pragma unroll
            for (int i = 0; i < 2; i++) {
                acc[i][j] = __builtin_amdgcn_mfma_f32_16x16x32_bf16(ah[i], bh_, acc[i][j], 0, 0, 0);
                acc[i][j] = __builtin_amdgcn_mfma_f32_16x16x32_bf16(ah[i], bl_, acc[i][j], 0, 0, 0);
                acc[i][j] = __builtin_amdgcn_mfma_f32_16x16x32_bf16(al[i], bh_, acc[i][j], 0, 0, 0);
            }
        }
        __syncthreads();
    }

    if (EPI == 0) {
#pragma unroll
        for (int i = 0; i < 2; i++) {
            const int mrow = bm + w * 32 + i * 16 + (l >> 4) * 4;
#pragma unroll
            for (int j = 0; j < 4; j++) {
                const int col = bn + j * 16 + ln;
                const float bb = bias[col];
#pragma unroll
                for (int r = 0; r < 4; r++)
                    C[(size_t)(mrow + r) * N + col] = (acc[i][j][r] + bb) * scale;
            }
        }
    } else {
        // head-transposed write; 128-row tile lies within one batch
        const int bblk = bm >> 10;               // row0/Sq
        const int sbase = (bm & (Sq - 1));
#pragma unroll
        for (int i = 0; i < 2; i++) {
            const int s0 = sbase + w * 32 + i * 16 + (l >> 4) * 4;
#pragma unroll
            for (int j = 0; j < 4; j++) {
                const int col = bn + j * 16 + ln;   // h*D + d
                const int h = col >> 6;
                const int d = col & (Dq - 1);
                const float bb = bias[col];
                float4 o;
                o.x = (acc[i][j][0] + bb) * scale;
                o.y = (acc[i][j][1] + bb) * scale;
                o.z = (acc[i][j][2] + bb) * scale;
                o.w = (acc[i][j][3] + bb) * scale;
                *(float4*)(C + (size_t)((bblk * Hq + h) * Dq + d) * Sq + s0) = o;
            }
        }
    }
}

// ---------------------------------------------------------------------------
// PV: same split-bf16 MFMA skeleton, batched per (b,h):
// AO[b,q,h*64+d] = sum_k W[b,h,q,k] * Vt[(b*H+h)*64+d][k]
// A = W slice [1024,1024], B^T = Vt slice [64,1024]. Tile 128x64, BK=32.
// Grid (1024/128=8, 64 bh) = 512 blocks.
// ---------------------------------------------------------------------------
__global__ __launch_bounds__(256, 2) void attn_pv_mfma(
    const float* __restrict__ W,   // [B,H,S,S]
    const float* __restrict__ Vt,  // [B*H*D, S]
    float* __restrict__ AO)        // [B*S, E]
{
    __shared__ unsigned short Ah[BM][LPAD];
    __shared__ unsigned short Al[BM][LPAD];
    __shared__ unsigned short Bh[BN][LPAD];
    __shared__ unsigned short Bl[BN][LPAD];

    const int bm = blockIdx.x * BM;     // q tile base
    const int bh = blockIdx.y;          // 0..63
    const int h  = bh & (Hq - 1);
    const int b  = bh >> 4;

    const float* Ap = W  + (size_t)bh * Sq * Sq;
    const float* Bp = Vt + (size_t)bh * Dq * Sq;

    const int t  = threadIdx.x;
    const int l  = t & 63;
    const int w  = t >> 6;
    const int ln = l & 15;
    const int ko = (l >> 4) * 8;
    const int r0 = t >> 3;
    const int kc = (t & 7) * 4;

    f32x4 acc[2][4] = {};

#pragma unroll 1
    for (int k0 = 0; k0 < Sq; k0 += BKK) {
#pragma unroll
        for (int rr = 0; rr < 4; rr++) {
            const int m = r0 + 32 * rr;
            float4 v = *(const float4*)(Ap + (size_t)(bm + m) * Sq + k0 + kc);
            uint2 hp, lp; cvt_hl(v, &hp, &lp);
            *(uint2*)&Ah[m][kc] = hp;
            *(uint2*)&Al[m][kc] = lp;
        }
#pragma unroll
        for (int rr = 0; rr < 2; rr++) {
            const int n = r0 + 32 * rr;   // d
            float4 v = *(const float4*)(Bp + (size_t)n * Sq + k0 + kc);
            uint2 hp, lp; cvt_hl(v, &hp, &lp);
            *(uint2*)&Bh[n][kc] = hp;
            *(uint2*)&Bl[n][kc] = lp;
        }
        __syncthreads();

        bf16x8 ah[2], al[2];
#pragma unroll
        for (int i = 0; i < 2; i++) {
            const int m = w * 32 + i * 16 + ln;
            ah[i] = *(const bf16x8*)&Ah[m][ko];
            al[i] = *(const bf16x8*)&Al[m][ko];
        }
#pragma unroll
        for (int j = 0; j < 4; j++) {
            const int n = j * 16 + ln;
            const bf16x8 bh_ = *(const bf16x8*)&Bh[n][ko];
            const bf16x8 bl_ = *(const bf16x8*)&Bl[n][ko];
#pragma unroll
            for (int i = 0; i < 2; i++) {
                acc[i][j] = __builtin_amdgcn_mfma_f32_16x16x32_bf16(ah[i], bh_, acc[i][j], 0, 0, 0);
                acc[i][j] = __builtin_amdgcn_mfma_f32_16x16x32_bf16(ah[i], bl_, acc[i][j], 0, 0, 0);
                acc[i][j] = __builtin_amdgcn_mfma_f32_16x16x32_bf16(al[i], bh_, acc[i][j], 0, 0, 0);
            }
        }
        __syncthreads();
    }

#pragma unroll
    for (int i = 0; i < 2; i++) {
        const int q0 = bm + w * 32 + i * 16 + (l >> 4) * 4;
#pragma unroll
        for (int j = 0; j < 4; j++) {
            const int d = j * 16 + ln;
#pragma unroll
            for (int r = 0; r < 4; r++)
                AO[(size_t)(b * Sq + q0 + r) * Eq + h * Dq + d] = acc[i][j][r];
        }
    }
}

// ---------------------------------------------------------------------------
// Scores + softmax (r4-measured: 286us, VALU 48%, VGPR 36 — unchanged).
// ---------------------------------------------------------------------------
#define QB 8

__global__ __launch_bounds__(256, 2) void attn_scores(
    const float* __restrict__ Q,     // [B*S, E] (pre-scaled)
    const float* __restrict__ Kt,    // [B*H*D, S] head-transposed K
    const float* __restrict__ bias,  // [B,H,S,S]
    const int*   __restrict__ mask,  // [B,S]
    float* __restrict__ W)           // [B,H,S,S]
{
    const int bid = blockIdx.x;
    const int qc = bid & (Sq / QB - 1);       // 0..127
    const int h  = (bid >> 7) & (Hq - 1);
    const int b  = bid >> 11;
    const int q0 = qc * QB;

    __shared__ __align__(16) float qs[QB][Dq];
    __shared__ float redm[QB][4];
    __shared__ float reds[QB][4];

    const int t = threadIdx.x;

    if (t < 128) {
        const int qq = t >> 4;
        const int c4 = t & 15;
        ((float4*)qs[qq])[c4] =
            *(const float4*)(Q + ((size_t)(b * Sq + q0 + qq)) * Eq + h * Dq + c4 * 4);
    }
    __syncthreads();

    const float* Ktp = Kt + (size_t)(b * Hq + h) * Dq * Sq;

    float sc[4][QB];
#pragma unroll
    for (int j = 0; j < 4; j++)
#pragma unroll
        for (int qq = 0; qq < QB; qq++) sc[j][qq] = 0.f;

#pragma unroll 1
    for (int d = 0; d < Dq; d++) {
        const float4 kt = *(const float4*)(Ktp + (size_t)d * Sq + 4 * t);
#pragma unroll
        for (int qq = 0; qq < QB; qq++) {
            const float qv = qs[qq][d];
            sc[0][qq] += kt.x * qv;
            sc[1][qq] += kt.y * qv;
            sc[2][qq] += kt.z * qv;
            sc[3][qq] += kt.w * qv;
        }
    }

    const int*  mrow = mask + b * Sq;
    const int4  mv   = *(const int4*)(mrow + 4 * t);
    const float* biasBase = bias + ((size_t)(b * Hq + h) * Sq + q0) * Sq;

    float mx[QB];
#pragma unroll
    for (int qq = 0; qq < QB; qq++) {
        const float4 bv = *(const float4*)(biasBase + (size_t)qq * Sq + 4 * t);
        float d0 = (mv.x != 0) ? -INFINITY : (sc[0][qq] + bv.x);
        float d1 = (mv.y != 0) ? -INFINITY : (sc[1][qq] + bv.y);
        float d2 = (mv.z != 0) ? -INFINITY : (sc[2][qq] + bv.z);
        float d3 = (mv.w != 0) ? -INFINITY : (sc[3][qq] + bv.w);
        sc[0][qq] = d0; sc[1][qq] = d1; sc[2][qq] = d2; sc[3][qq] = d3;
        mx[qq] = fmaxf(fmaxf(d0, d1), fmaxf(d2, d3));
    }

    const int lane = t & 63;
    const int wid  = t >> 6;

#pragma unroll
    for (int off = 32; off > 0; off >>= 1)
#pragma unroll
        for (int qq = 0; qq < QB; qq++)
            mx[qq] = fmaxf(mx[qq], __shfl_xor(mx[qq], off));
    if (lane == 0) {
#pragma unroll
        for (int qq = 0; qq < QB; qq++) redm[qq][wid] = mx[qq];
    }
    __syncthreads();
#pragma unroll
    for (int qq = 0; qq < QB; qq++)
        mx[qq] = fmaxf(fmaxf(redm[qq][0], redm[qq][1]),
                       fmaxf(redm[qq][2], redm[qq][3]));

    float ls[QB];
#pragma unroll
    for (int qq = 0; qq < QB; qq++) ls[qq] = 0.f;
#pragma unroll
    for (int j = 0; j < 4; j++)
#pragma unroll
        for (int qq = 0; qq < QB; qq++) {
            const float e = __expf(sc[j][qq] - mx[qq]);
            sc[j][qq] = e;
            ls[qq] += e;
        }

#pragma unroll
    for (int off = 32; off > 0; off >>= 1)
#pragma unroll
        for (int qq = 0; qq < QB; qq++)
            ls[qq] += __shfl_xor(ls[qq], off);
    if (lane == 0) {
#pragma unroll
        for (int qq = 0; qq < QB; qq++) reds[qq][wid] = ls[qq];
    }
    __syncthreads();

    float inv[QB];
#pragma unroll
    for (int qq = 0; qq < QB; qq++)
        inv[qq] = 1.0f / (reds[qq][0] + reds[qq][1] + reds[qq][2] + reds[qq][3]);

    float* wBase = W + ((size_t)(b * Hq + h) * Sq + q0) * Sq;
#pragma unroll
    for (int qq = 0; qq < QB; qq++) {
        float4 o;
        o.x = sc[0][qq] * inv[qq];
        o.y = sc[1][qq] * inv[qq];
        o.z = sc[2][qq] * inv[qq];
        o.w = sc[3][qq] * inv[qq];
        *(float4*)(wBase + (size_t)qq * Sq + 4 * t) = o;
    }
}

// ---------------------------------------------------------------------------
extern "C" void kernel_launch(void* const* d_in, const int* in_sizes, int n_in,
                              void* d_out, int out_size, void* d_ws, size_t ws_size,
                              hipStream_t stream) {
    const float* x         = (const float*)d_in[0];
    const float* attn_bias = (const float*)d_in[1];
    const int*   mask      = (const int*)d_in[2];
    const float* Wq = (const float*)d_in[3];
    const float* bq = (const float*)d_in[4];
    const float* Wk = (const float*)d_in[5];
    const float* bk = (const float*)d_in[6];
    const float* Wv = (const float*)d_in[7];
    const float* bv = (const float*)d_in[8];
    const float* Wo = (const float*)d_in[9];
    const float* bo = (const float*)d_in[10];

    float* out    = (float*)d_out;                       // [B,S,E]
    float* attn_w = out + (size_t)Bq * Sq * Eq;          // [B,H,S,S]

    const size_t rows = (size_t)Bq * Sq;                 // 4096
    float* Q  = (float*)d_ws;                            // [4096,1024]
    float* Kt = Q + rows * Eq;                           // [B*H*D, S]
    float* Vt = Kt + rows * Eq;                          // [B*H*D, S]
    float* AO = Q;  // reuse Q's slot after scores are done

    const dim3 gemm_grid(Eq / BN, (int)(rows / BM));     // 16 x 32 = 512 blocks
    const float scaling = 0.125f;                        // D^-0.5

    gemm_mfma<0><<<gemm_grid, 256, 0, stream>>>(x, Wq, bq, Q,  (int)rows, Eq, Eq, scaling);
    gemm_mfma<1><<<gemm_grid, 256, 0, stream>>>(x, Wk, bk, Kt, (int)rows, Eq, Eq, 1.0f);
    gemm_mfma<1><<<gemm_grid, 256, 0, stream>>>(x, Wv, bv, Vt, (int)rows, Eq, Eq, 1.0f);

    attn_scores<<<Bq * Hq * (Sq / QB), 256, 0, stream>>>(Q, Kt, attn_bias, mask, attn_w);

    const dim3 pv_grid(Sq / BM, Bq * Hq);                // 8 x 64 = 512 blocks
    attn_pv_mfma<<<pv_grid, 256, 0, stream>>>(attn_w, Vt, AO);

    gemm_mfma<0><<<gemm_grid, 256, 0, stream>>>(AO, Wo, bo, out, (int)rows, Eq, Eq, 1.0f);
}